// Round 11
// baseline (73.885 us; speedup 1.0000x reference)
//
#include <hip/hip_runtime.h>
#include <stdint.h>

// Fused BSQ: recon = sign(x @ Wp + bp) @ Wr + br   (L2-normalize is sign-invariant)
// x: [65536][512] f32, Wp: [512][16], bp: [16], Wr: [16][512], br: [512]
//
// Round-11 = round-10 minus the (measured-neutral) dot/recon interleave,
// plus float4 stores:
//  - Phase A: DMA ring (4 slots x 2 rows), counted WAITV(3) steady state,
//    one-time WAITV(0) after the initial stages (kills the straggler-load
//    miscount hazard), pk-FMA dot, 1 shfl-pair reduce, zp[row][d][wave].
//  - Phase B (sequential, wp dead -> wr4 float4[16] = 64 VGPR fits): each
//    row-PAIR per pass; waves 0,1 recon row 2rp, waves 2,3 row 2rp+1; one
//    ds_read_b128 of zp + 16 pk-FMA + ONE b128 store per lane (16B/lane
//    coalescing, half the store instructions of round 10).
//  - Ambiguity (|z|<TAU) ballots are per-wave now -> OR-merged via LDS, then
//    the cooperative exact-f64 fixup (rare, ~2%) redoes those rows with
//    row-parity-predicated stores. Reference signs are f64-exact (r1-10
//    absmax 0.0). __launch_bounds__(256,2), natural regalloc.

#define ROWS   65536
#define TILE   32
#define BLOCKS (ROWS / TILE)   // 2048
#define TAU    1e-3f

#define BAR()    asm volatile("s_waitcnt lgkmcnt(0)\n\ts_barrier" ::: "memory")
#define WAITV(N) asm volatile("s_waitcnt vmcnt(" #N ")" ::: "memory")
#define WAITL()  asm volatile("s_waitcnt lgkmcnt(0)" ::: "memory")
#define CFENCE() asm volatile("" ::: "memory")

typedef const __attribute__((address_space(1))) void* gas1_t;
typedef __attribute__((address_space(3))) void*       las3_t;
typedef float v2f __attribute__((ext_vector_type(2)));

__global__ __launch_bounds__(256, 2)
void bsq_fused(const float* __restrict__ x,
               const float* __restrict__ Wp,
               const float* __restrict__ bp,
               const float* __restrict__ Wr,
               const float* __restrict__ br,
               float* __restrict__ out)
{
    const int tid = threadIdx.x;
    const int w   = tid >> 6;      // wave 0..3
    const int l   = tid & 63;
    const int cg  = l >> 4;        // 0..3 : c-subgroup (phase A)
    const int dg  = l & 15;        // 0..15: this lane's d

    __shared__ __align__(16) float    xl[4 * 1024];     // 16 KB ring
    __shared__ __align__(16) float    zp[TILE][16][4];  // 8 KB [row][d][wave]
    __shared__ __align__(16) double   zb64[4][16];      // fixup exchange
    __shared__            uint32_t    ambx[4];          // per-wave amb masks

    // ---- phase-A weights as v2f pairs ----
    v2f wpA[8], wpB[8];
#pragma unroll
    for (int j = 0; j < 8; ++j) {
        const float* wj = Wp + (w * 128 + j * 16 + cg * 4) * 16 + dg;
        wpA[j] = (v2f){ wj[0],  wj[16] };
        wpB[j] = (v2f){ wj[32], wj[48] };
    }
    const float bpf = bp[dg];

    const int row0 = blockIdx.x * TILE;
    const float* xsrc = x + (size_t)row0 * 512 + (size_t)(l >> 5) * 512
                          + w * 128 + (l & 31) * 4;

    auto stage = [&](int s) {      // rows 2s,2s+1: wave's 1 KB region, 1 DMA
        __builtin_amdgcn_global_load_lds(
            (gas1_t)(xsrc + (size_t)(2 * s) * 512),
            (las3_t)(&xl[(s & 3) * 1024 + w * 256]), 16, 0, 0);
    };

    auto dot_part = [&](int s, int p, v2f& accA, v2f& accB) {
        const float* bx = &xl[(s & 3) * 1024 + w * 256 + p * 128 + cg * 4];
        float4 xr[8];
#pragma unroll
        for (int j = 0; j < 8; ++j) xr[j] = *(const float4*)(bx + j * 16);
        accA = (v2f){0.f, 0.f};  accB = (v2f){0.f, 0.f};
#pragma unroll
        for (int j = 0; j < 8; ++j) {
            accA += (v2f){ xr[j].x, xr[j].y } * wpA[j];   // v_pk_fma_f32
            accB += (v2f){ xr[j].z, xr[j].w } * wpB[j];
        }
    };
    auto fin_part = [&](int r, v2f accA, v2f accB) {
        float a = (accA.x + accA.y) + (accB.x + accB.y);
        a += __shfl_xor(a, 16, 64);
        a += __shfl_xor(a, 32, 64);
        if (l < 16) zp[r][l][w] = a;   // 2-way bank alias = free
    };

    // ================= Phase A: signs (no barriers) =================
#pragma unroll
    for (int s = 0; s < 4; ++s) stage(s);
    WAITV(0);   // one-time drain: weight loads + stages 0..3 retired.
                // From here each chunk adds exactly 1 DMA -> WAITV(3) is exact
                // regardless of any compiler-sunk straggler loads.

#pragma unroll 1
    for (int c = 0; c < 12; ++c) {
        WAITV(3);                  // stage(c) retired (newest-3 = c+1..c+3)
        v2f aA0, aB0, aA1, aB1;
        dot_part(c, 0, aA0, aB0);
        dot_part(c, 1, aA1, aB1);
        CFENCE();
        WAITL();                   // slot's ds_reads retired -> reusable
        stage(c + 4);
        CFENCE();
        fin_part(2 * c, aA0, aB0);
        fin_part(2 * c + 1, aA1, aB1);
    }
    {
        v2f aA0, aB0, aA1, aB1;
        WAITV(3); dot_part(12, 0, aA0, aB0); dot_part(12, 1, aA1, aB1);
        fin_part(24, aA0, aB0); fin_part(25, aA1, aB1);
        WAITV(2); dot_part(13, 0, aA0, aB0); dot_part(13, 1, aA1, aB1);
        fin_part(26, aA0, aB0); fin_part(27, aA1, aB1);
        WAITV(1); dot_part(14, 0, aA0, aB0); dot_part(14, 1, aA1, aB1);
        fin_part(28, aA0, aB0); fin_part(29, aA1, aB1);
        WAITV(0); dot_part(15, 0, aA0, aB0); dot_part(15, 1, aA1, aB1);
        fin_part(30, aA0, aB0); fin_part(31, aA1, aB1);
    }
    BAR();   // zp visible to all waves

    // ---- phase-B weights (wp dead; float4 slices, 64 VGPR) ----
    const int col = tid & 127;         // float4 column within a row
    float4 wr4[16];
#pragma unroll
    for (int d = 0; d < 16; ++d) wr4[d] = ((const float4*)Wr)[d * 128 + col];
    const float4 br4 = ((const float4*)br)[col];
    const int rp_row = tid >> 7;       // 0: waves 0,1   1: waves 2,3

    // ============ Phase B: recon, one row-PAIR per pass ============
    uint32_t amb = 0;                  // per-wave ambiguity mask
#pragma unroll 4
    for (int rp = 0; rp < 16; ++rp) {
        const int r = 2 * rp + rp_row;
        const float4 q = *(const float4*)&zp[r][dg][0];
        const float  z = (q.x + q.y) + (q.z + q.w) + bpf;
        if (__ballot(fabsf(z) < TAU)) amb |= (1u << r);
        const int m = (int)(__ballot(z >= 0.0f) & 0xFFFFull);  // wave-uniform

        v2f o01 = { br4.x, br4.y }, o23 = { br4.z, br4.w };
#pragma unroll
        for (int d = 0; d < 16; ++d) {
            const float s = ((m >> d) & 1) ? 1.0f : -1.0f;
            const v2f sv = { s, s };
            o01 += sv * (v2f){ wr4[d].x, wr4[d].y };   // v_pk_fma_f32
            o23 += sv * (v2f){ wr4[d].z, wr4[d].w };
        }
        ((float4*)out)[(size_t)(row0 + r) * 128 + col] =
            make_float4(o01.x, o01.y, o23.x, o23.y);
    }

    // ---- merge per-wave ambiguity masks (block-uniform fixup set) ----
    if (l == 0) ambx[w] = amb;
    BAR();
    uint32_t amb_all = ambx[0] | ambx[1] | ambx[2] | ambx[3];

    // ===== Fixup: rare exact-f64 redo; uniform loop, matched barriers =====
    const double bpd = (double)bpf;
#pragma unroll 1
    while (amb_all) {
        const int rr = __ffs(amb_all) - 1;
        amb_all &= amb_all - 1;
        const int row = row0 + rr;

        const float* xp = x + (size_t)row * 512 + w * 128 + cg * 4;
        double ad = 0.0;
#pragma unroll
        for (int j = 0; j < 8; ++j) {
            const float4 xf = *(const float4*)(xp + j * 16);
#pragma unroll
            for (int e = 0; e < 4; ++e) {
                const float wpe = Wp[(w * 128 + j * 16 + cg * 4 + e) * 16 + dg];
                const float xe  = e == 0 ? xf.x : e == 1 ? xf.y
                               : e == 2 ? xf.z : xf.w;
                ad = fma((double)xe, (double)wpe, ad);
            }
        }
        ad += __shfl_xor(ad, 16, 64);
        ad += __shfl_xor(ad, 32, 64);
        if (l < 16) zb64[w][l] = ad;
        BAR();
        const double zd = (zb64[0][dg] + zb64[1][dg])
                        + (zb64[2][dg] + zb64[3][dg]) + bpd;
        const int m = (int)(__ballot(zd >= 0.0) & 0xFFFFull);
        BAR();   // zb64 reads retired before next fixup row's rewrite

        v2f o01 = { br4.x, br4.y }, o23 = { br4.z, br4.w };
#pragma unroll
        for (int d = 0; d < 16; ++d) {
            const float s = ((m >> d) & 1) ? 1.0f : -1.0f;
            const v2f sv = { s, s };
            o01 += sv * (v2f){ wr4[d].x, wr4[d].y };
            o23 += sv * (v2f){ wr4[d].z, wr4[d].w };
        }
        if (rp_row == (rr & 1))   // the half-block that owns this row parity
            ((float4*)out)[(size_t)row * 128 + col] =
                make_float4(o01.x, o01.y, o23.x, o23.y);
    }
}

extern "C" void kernel_launch(void* const* d_in, const int* in_sizes, int n_in,
                              void* d_out, int out_size, void* d_ws, size_t ws_size,
                              hipStream_t stream) {
    const float* x  = (const float*)d_in[0];
    const float* Wp = (const float*)d_in[1];
    const float* bp = (const float*)d_in[2];
    const float* Wr = (const float*)d_in[3];
    const float* br = (const float*)d_in[4];
    float* out = (float*)d_out;

    bsq_fused<<<BLOCKS, 256, 0, stream>>>(x, Wp, bp, Wr, br, out);
}

// Round 12
// 63.812 us; speedup vs baseline: 1.1578x; 1.1578x over previous
//
#include <hip/hip_runtime.h>
#include <stdint.h>

// Fused BSQ: recon = sign(x @ Wp + bp) @ Wr + br   (L2-normalize is sign-invariant)
// x: [65536][512] f32, Wp: [512][16], bp: [16], Wr: [16][512], br: [512]
//
// Round-12 = round-10 (best: 64.7us, VGPR 64) with TILE 32->16:
//  - LDS 25 -> ~21 KB (ring 16KB + zp 4KB): 7 blocks/CU ceiling, 4096
//    finer-grain blocks -> better read/write stream interleave across CU.
//  - Simpler waits: prologue stages slots 0..3 (rows 0..7) + WAITV(0); first
//    half needs NO waits (chunk c's slot pre-drained), restages rows 8..15;
//    mid-BAR + wr-loads + WAITV(0) drains those; second half needs NO waits.
//    Two WAITV(0)/block total; counting immune to compiler-sunk loads.
//  - Recon of rows 0..7 interleaved into dot-chunks of rows 8..15 (r10
//    pattern), float2 stores, all-wave per-row recon (block-uniform masks).
//  - Rare exact-f64 fixup post-loop (block-uniform, matched barriers).
//    Reference signs are f64-exact: rounds 1-11 absmax 0.0.

#define ROWS   65536
#define TILE   16
#define BLOCKS (ROWS / TILE)   // 4096
#define TAU    1e-3f

#define BAR()    asm volatile("s_waitcnt lgkmcnt(0)\n\ts_barrier" ::: "memory")
#define WAITV(N) asm volatile("s_waitcnt vmcnt(" #N ")" ::: "memory")
#define WAITL()  asm volatile("s_waitcnt lgkmcnt(0)" ::: "memory")
#define CFENCE() asm volatile("" ::: "memory")

typedef const __attribute__((address_space(1))) void* gas1_t;
typedef __attribute__((address_space(3))) void*       las3_t;
typedef float v2f __attribute__((ext_vector_type(2)));

__global__ __launch_bounds__(256, 2)
void bsq_fused(const float* __restrict__ x,
               const float* __restrict__ Wp,
               const float* __restrict__ bp,
               const float* __restrict__ Wr,
               const float* __restrict__ br,
               float* __restrict__ out)
{
    const int tid = threadIdx.x;
    const int w   = tid >> 6;      // wave 0..3: c-quarter
    const int l   = tid & 63;
    const int cg  = l >> 4;        // 0..3
    const int dg  = l & 15;        // 0..15: this lane's d

    __shared__ __align__(16) float  xl[4 * 1024];     // 16 KB ring: 4 slots x 2 rows
    __shared__ __align__(16) float  zp[TILE][16][4];  // 4 KB: [row][d][wave]
    __shared__ __align__(16) double zb64[4][16];      // fixup exchange

    // ---- phase-A weights as v2f pairs (issued before the stages) ----
    v2f wpA[8], wpB[8];
#pragma unroll
    for (int j = 0; j < 8; ++j) {
        const float* wj = Wp + (w * 128 + j * 16 + cg * 4) * 16 + dg;
        wpA[j] = (v2f){ wj[0],  wj[16] };
        wpB[j] = (v2f){ wj[32], wj[48] };
    }
    const float bpf = bp[dg];

    const int row0 = blockIdx.x * TILE;
    const float* xsrc = x + (size_t)row0 * 512 + (size_t)(l >> 5) * 512
                          + w * 128 + (l & 31) * 4;

    auto stage = [&](int s) {      // rows 2s,2s+1: wave's 1 KB region, 1 DMA
        __builtin_amdgcn_global_load_lds(
            (gas1_t)(xsrc + (size_t)(2 * s) * 512),
            (las3_t)(&xl[(s & 3) * 1024 + w * 256]), 16, 0, 0);
    };

    auto dot_part = [&](int s, int p, v2f& accA, v2f& accB) {
        const float* bx = &xl[(s & 3) * 1024 + w * 256 + p * 128 + cg * 4];
        float4 xr[8];
#pragma unroll
        for (int j = 0; j < 8; ++j) xr[j] = *(const float4*)(bx + j * 16);
        accA = (v2f){0.f, 0.f};  accB = (v2f){0.f, 0.f};
#pragma unroll
        for (int j = 0; j < 8; ++j) {
            accA += (v2f){ xr[j].x, xr[j].y } * wpA[j];   // v_pk_fma_f32
            accB += (v2f){ xr[j].z, xr[j].w } * wpB[j];
        }
    };
    auto fin_part = [&](int r, v2f accA, v2f accB) {
        float a = (accA.x + accA.y) + (accB.x + accB.y);
        a += __shfl_xor(a, 16, 64);    // reduce over cg (lane bits 4,5)
        a += __shfl_xor(a, 32, 64);
        if (l < 16) zp[r][l][w] = a;   // 2-way bank alias = free
    };

    // ========== Phase A first half: rows 0..7 (pure dots) ==========
#pragma unroll
    for (int s = 0; s < 4; ++s) stage(s);
    WAITV(0);   // weights + slots 0..3 all resident; counting now exact

#pragma unroll 1
    for (int c = 0; c < 4; ++c) {
        v2f aA0, aB0, aA1, aB1;
        dot_part(c, 0, aA0, aB0);      // slot pre-drained, no wait
        dot_part(c, 1, aA1, aB1);
        CFENCE();
        WAITL();                       // slot's ds_reads retired -> reusable
        stage(c + 4);                  // rows 8..15 back into slots 0..3
        CFENCE();
        fin_part(2 * c, aA0, aB0);
        fin_part(2 * c + 1, aA1, aB1);
    }
    BAR();                             // zp rows 0..7 visible (lgkm-only)

    // ---- phase-B weights (v2f float2 slices; VGPR stays ~64) ----
    v2f wrv[16];
    const float2* Wr2 = (const float2*)Wr;
#pragma unroll
    for (int d = 0; d < 16; ++d) {
        const float2 t = Wr2[d * 256 + tid];
        wrv[d] = (v2f){ t.x, t.y };
    }
    const float2 brt = ((const float2*)br)[tid];
    const v2f br2v = (v2f){ brt.x, brt.y };
    WAITV(0);   // drains stages 4..7 + wr loads -> second half waits-free

    uint32_t amb = 0;                  // block-uniform ambiguity mask
    auto recon_row = [&](int r) {
        const float4 q = *(const float4*)&zp[r][dg][0];   // 1 b128, conflict-free
        const float  z = (q.x + q.y) + (q.z + q.w) + bpf;
        if (__ballot(fabsf(z) < TAU)) amb |= (1u << r);
        const int m = (int)(__ballot(z >= 0.0f) & 0xFFFFull);
        v2f o = br2v;
#pragma unroll
        for (int d = 0; d < 16; ++d) {
            const float s = ((m >> d) & 1) ? 1.0f : -1.0f;
            o += (v2f){ s, s } * wrv[d];                  // v_pk_fma_f32
        }
        ((float2*)out)[(size_t)(row0 + r) * 256 + tid] = make_float2(o.x, o.y);
    };

    // == Phase A second half (rows 8..15) interleaved with recon rows 0..7 ==
#pragma unroll 1
    for (int c = 4; c < 8; ++c) {
        v2f aA0, aB0, aA1, aB1;
        dot_part(c, 0, aA0, aB0);      // slots pre-drained by WAITV(0)
        dot_part(c, 1, aA1, aB1);
        fin_part(2 * c, aA0, aB0);
        fin_part(2 * c + 1, aA1, aB1);
        recon_row(2 * (c - 4));
        recon_row(2 * (c - 4) + 1);
    }
    BAR();                             // zp rows 8..15 visible

    // ============ Phase B tail: recon rows 8..15 ============
#pragma unroll 2
    for (int r = 8; r < TILE; ++r) recon_row(r);

    // ===== Fixup: rare exact-f64 redo; uniform loop, matched barriers =====
    const double bpd = (double)bpf;
#pragma unroll 1
    while (amb) {
        const int rr = __ffs(amb) - 1;
        amb &= amb - 1;
        const int row = row0 + rr;

        const float* xp = x + (size_t)row * 512 + w * 128 + cg * 4;
        double ad = 0.0;
#pragma unroll
        for (int j = 0; j < 8; ++j) {
            const float4 xf = *(const float4*)(xp + j * 16);
#pragma unroll
            for (int e = 0; e < 4; ++e) {
                const float wpe = Wp[(w * 128 + j * 16 + cg * 4 + e) * 16 + dg];
                const float xe  = e == 0 ? xf.x : e == 1 ? xf.y
                               : e == 2 ? xf.z : xf.w;
                ad = fma((double)xe, (double)wpe, ad);
            }
        }
        ad += __shfl_xor(ad, 16, 64);
        ad += __shfl_xor(ad, 32, 64);
        if (l < 16) zb64[w][l] = ad;
        BAR();
        const double zd = (zb64[0][dg] + zb64[1][dg])
                        + (zb64[2][dg] + zb64[3][dg]) + bpd;
        const int m = (int)(__ballot(zd >= 0.0) & 0xFFFFull);
        BAR();   // zb64 reads retired before next fixup row's rewrite

        v2f o = br2v;
#pragma unroll
        for (int d = 0; d < 16; ++d) {
            const float s = ((m >> d) & 1) ? 1.0f : -1.0f;
            o += (v2f){ s, s } * wrv[d];
        }
        ((float2*)out)[(size_t)row * 256 + tid] = make_float2(o.x, o.y);
    }
}

extern "C" void kernel_launch(void* const* d_in, const int* in_sizes, int n_in,
                              void* d_out, int out_size, void* d_ws, size_t ws_size,
                              hipStream_t stream) {
    const float* x  = (const float*)d_in[0];
    const float* Wp = (const float*)d_in[1];
    const float* bp = (const float*)d_in[2];
    const float* Wr = (const float*)d_in[3];
    const float* br = (const float*)d_in[4];
    float* out = (float*)d_out;

    bsq_fused<<<BLOCKS, 256, 0, stream>>>(x, Wp, bp, Wr, br, out);
}